// Round 11
// baseline (255.247 us; speedup 1.0000x reference)
//
#include <hip/hip_runtime.h>
#include <hip/hip_bf16.h>
#include <hip/hip_fp16.h>
#include <math.h>

#define B_    32
#define T_    512
#define D_    512
#define P_    200
#define NP_   8
#define N_TOT 1600
#define NEG_  (-100000.0f)
#define LO_SCALE 2048.0f
#define LO_INV   (1.0f/2048.0f)

typedef __attribute__((ext_vector_type(8))) _Float16 f16x8;
typedef __attribute__((ext_vector_type(4))) _Float16 f16x4;
typedef __attribute__((ext_vector_type(4))) float   f32x4;
typedef unsigned long long u64;

// global -> LDS direct copy, 16B per lane; LDS dest = wave-uniform base + lane*16
#define GLL16(gp, lp) __builtin_amdgcn_global_load_lds( \
    (const __attribute__((address_space(1))) void*)(gp), \
    (__attribute__((address_space(3))) void*)(lp), 16, 0, 0)

__device__ __forceinline__ float wave_reduce_sum(float v) {
#pragma unroll
  for (int off = 32; off; off >>= 1) v += __shfl_xor(v, off, 64);
  return v;
}

// monotone f32 -> u32 order transform and inverse
__device__ __forceinline__ unsigned ordf(float f) {
  unsigned u = __float_as_uint(f);
  return (u & 0x80000000u) ? ~u : (u | 0x80000000u);
}
__device__ __forceinline__ float deco(unsigned o) {
  unsigned u = (o & 0x80000000u) ? (o ^ 0x80000000u) : ~o;
  return __uint_as_float(u);
}
// pack: value-major, inverted key (smaller key wins ties). key = i*512 + t < 4096.
__device__ __forceinline__ u64 packvk(float v, int key) {
  return ((u64)ordf(v) << 32) | (u64)(4095 - key);
}

// ---- fused normalize: blocks [0,4096) do x rows; [4096,4496) do prototypes ----
__global__ __launch_bounds__(256) void norm_fused(const float* __restrict__ x,
                                                  const float* __restrict__ proto,
                                                  _Float16* __restrict__ xh,
                                                  _Float16* __restrict__ xl,
                                                  _Float16* __restrict__ wh,
                                                  _Float16* __restrict__ wl,
                                                  u64* __restrict__ slotbuf) {
  int lane = threadIdx.x & 63;
  if (blockIdx.x < B_ * T_ / 4) {
    int row = blockIdx.x * 4 + (threadIdx.x >> 6);   // 0..16383
    const float* xr = x + (size_t)row * D_;
    float4 v0 = *(const float4*)(xr + lane * 4);
    float4 v1 = *(const float4*)(xr + 256 + lane * 4);
    float s = v0.x*v0.x + v0.y*v0.y + v0.z*v0.z + v0.w*v0.w
            + v1.x*v1.x + v1.y*v1.y + v1.z*v1.z + v1.w*v1.w;
    s = wave_reduce_sum(s);
    float dn = fmaxf(sqrtf(s), 1e-12f);
    float f[8] = {v0.x/dn, v0.y/dn, v0.z/dn, v0.w/dn, v1.x/dn, v1.y/dn, v1.z/dn, v1.w/dn};
    f16x4 h0, h1, l0, l1;
#pragma unroll
    for (int j = 0; j < 4; j++) {
      h0[j] = (_Float16)f[j];
      l0[j] = (_Float16)((f[j] - (float)h0[j]) * LO_SCALE);
      h1[j] = (_Float16)f[4 + j];
      l1[j] = (_Float16)((f[4 + j] - (float)h1[j]) * LO_SCALE);
    }
    size_t base = (size_t)row * D_;
    *(f16x4*)(xh + base + lane * 4)       = h0;
    *(f16x4*)(xh + base + 256 + lane * 4) = h1;
    *(f16x4*)(xl + base + lane * 4)       = l0;
    *(f16x4*)(xl + base + 256 + lane * 4) = l1;
  } else {
    int wb = blockIdx.x - B_ * T_ / 4;               // 0..399
    if (wb == 0) {   // zero raw+q slots; completes before gemm in-stream
      for (int i = threadIdx.x; i < 2 * B_ * P_; i += 256) slotbuf[i] = 0ULL;
    }
    int n = wb * 4 + (threadIdx.x >> 6);             // 0..1599
    int p = n >> 3, i = n & 7;
    float v[8];
    float s = 0.f;
#pragma unroll
    for (int k = 0; k < 8; k++) {
      int d = k * 64 + lane;
      v[k] = proto[((size_t)p * D_ + d) * NP_ + i];
      s += v[k] * v[k];
    }
    s = wave_reduce_sum(s);
    float dn = fmaxf(sqrtf(s), 1e-12f);
    size_t base = (size_t)n * D_;
#pragma unroll
    for (int k = 0; k < 8; k++) {
      float f = v[k] / dn;
      _Float16 h = (_Float16)f;
      wh[base + k * 64 + lane] = h;
      wl[base + k * 64 + lane] = (_Float16)((f - (float)h) * LO_SCALE);
    }
  }
}

// ---- fp16-split MFMA GEMM + fused per-(b,p) argmax slots ----
// Scaled-up r5-measured-best structure: 256(n) x 128(t) tile, 8 waves (512 thr),
// symmetric chunked GLL16 staging, [row][32] LDS, single 48 KiB buffer, 2
// barriers/K-step. vs r10's 128x128: staging bytes per output -25%, 384 MFMA
// per barrier (2x). (512,2): VGPR cap 256, no r7-style allocator squeeze.
__global__ __launch_bounds__(512, 2) void gemm_mfma(
    const _Float16* __restrict__ XH, const _Float16* __restrict__ XL,
    const _Float16* __restrict__ WH, const _Float16* __restrict__ WL,
    const float* __restrict__ tm, float* __restrict__ dist,
    u64* __restrict__ rawslot, u64* __restrict__ qslot) {
  __shared__ _Float16 lds[24576];   // 48 KiB: Ah[0] Ah[1] | Al[0] Al[1] | Xh | Xl
  const int b  = blockIdx.z;
  const int n0 = blockIdx.y * 256;
  const int t0 = blockIdx.x * 128;
  const int tid = threadIdx.x;      // 0..511
  const int w = tid >> 6, l = tid & 63;

  // A: 1024 chunks of 16B (256 rows x 4), lane tid does chunks {tid, 512+tid}.
  // chunk c -> row c>>2, k-off (c&3)*8; LDS elem offset c*8 == [row][32] layout.
  int ra0 = tid >> 2,         ka0 = (tid & 3) * 8;
  int ra1 = (512 + tid) >> 2, ka1 = (tid & 3) * 8;    // (512+tid)&3 == tid&3
  int an0 = n0 + ra0; if (an0 > N_TOT - 1) an0 = N_TOT - 1;  // clamp; stores/slots guarded
  int an1 = n0 + ra1; if (an1 > N_TOT - 1) an1 = N_TOT - 1;
  const _Float16* pwh0 = WH + (size_t)an0 * D_ + ka0;
  const _Float16* pwh1 = WH + (size_t)an1 * D_ + ka1;
  const _Float16* pwl0 = WL + (size_t)an0 * D_ + ka0;
  const _Float16* pwl1 = WL + (size_t)an1 * D_ + ka1;
  // X: 512 chunks (128 rows x 4), lane tid does chunk tid.
  int rx = tid >> 2, kx = (tid & 3) * 8;
  const _Float16* pxh = XH + ((size_t)b * T_ + t0 + rx) * D_ + kx;
  const _Float16* pxl = XL + ((size_t)b * T_ + t0 + rx) * D_ + kx;
  // LDS dests: wave-uniform base + l*8 elems (16B/lane linear, GLL16 requirement)
  _Float16* dAh0 = lds +     0 + w * 512;
  _Float16* dAh1 = lds +  4096 + w * 512;
  _Float16* dAl0 = lds +  8192 + w * 512;
  _Float16* dAl1 = lds + 12288 + w * 512;
  _Float16* dXh  = lds + 16384 + w * 512;
  _Float16* dXl  = lds + 20480 + w * 512;

  const int wn = (w >> 1) * 64;     // 0,64,128,192 : n-quadrant
  const int wt = (w & 1) * 64;      // 0,64         : t-half
  const int fr = l & 15, fq = l >> 4;

  f32x4 acch[4][4], accc[4][4];
#pragma unroll
  for (int m = 0; m < 4; m++)
#pragma unroll
    for (int n = 0; n < 4; n++) { acch[m][n] = (f32x4)0.0f; accc[m][n] = (f32x4)0.0f; }

  for (int kt = 0; kt < 16; ++kt) {
    const int k0 = kt * 32;
    GLL16(pwh0 + k0, dAh0); GLL16(pwh1 + k0, dAh1);
    GLL16(pwl0 + k0, dAl0); GLL16(pwl1 + k0, dAl1);
    GLL16(pxh  + k0, dXh);  GLL16(pxl  + k0, dXl);
    __syncthreads();                      // implicit vmcnt(0): LDS tile ready
    f16x8 ah[4], al[4], bh[4], bl[4];
#pragma unroll
    for (int m = 0; m < 4; m++) {
      int ro = (wn + m * 16 + fr) * 32 + fq * 8;
      ah[m] = *(const f16x8*)&lds[ro];
      al[m] = *(const f16x8*)&lds[8192 + ro];
    }
#pragma unroll
    for (int n = 0; n < 4; n++) {
      int ro = (wt + n * 16 + fr) * 32 + fq * 8;
      bh[n] = *(const f16x8*)&lds[16384 + ro];
      bl[n] = *(const f16x8*)&lds[20480 + ro];
    }
#pragma unroll
    for (int m = 0; m < 4; m++)
#pragma unroll
      for (int n = 0; n < 4; n++) {
        acch[m][n] = __builtin_amdgcn_mfma_f32_16x16x32_f16(ah[m], bh[n], acch[m][n], 0, 0, 0);
        accc[m][n] = __builtin_amdgcn_mfma_f32_16x16x32_f16(ah[m], bl[n], accc[m][n], 0, 0, 0);
        accc[m][n] = __builtin_amdgcn_mfma_f32_16x16x32_f16(al[m], bh[n], accc[m][n], 0, 0, 0);
      }
    __syncthreads();                      // protect buffer before next STAGE
  }

  // epilogue: combine, mask, store, and fused (max,first-key) reduction per p-group.
  // C/D: col = lane&15, row = (lane>>4)*4 + reg
  u64 pm[4], qm[4];
#pragma unroll
  for (int m = 0; m < 4; m++) { pm[m] = 0ULL; qm[m] = 0ULL; }
#pragma unroll
  for (int n = 0; n < 4; n++) {
    int col = t0 + wt + n * 16 + fr;   // global t
    float tmc = tm[b * T_ + col];
#pragma unroll
    for (int m = 0; m < 4; m++) {
      int nb = n0 + wn + m * 16 + fq * 4;
#pragma unroll
      for (int r = 0; r < 4; r++) {
        int nr = nb + r;
        if (nr < N_TOT) {
          float v = acch[m][n][r] + accc[m][n][r] * LO_INV;
          v = v * tmc + (1.0f - tmc) * NEG_;
          dist[((size_t)b * N_TOT + nr) * T_ + col] = v;
          int key = ((fq * 4 + r) & 7) * T_ + col;            // i*512 + t
          u64 pk = packvk(v, key);
          if (pk > pm[m]) pm[m] = pk;
          u64 qk = packvk(v + NEG_, key);                     // f32-quantized fallback
          if (qk > qm[m]) qm[m] = qk;
        }
      }
    }
  }
  // cross-lane: lanes 0-31 hold p-group 0 of each m, lanes 32-63 p-group 1
#pragma unroll
  for (int m = 0; m < 4; m++) {
#pragma unroll
    for (int off = 1; off <= 16; off <<= 1) {
      u64 o1 = __shfl_xor(pm[m], off, 64); if (o1 > pm[m]) pm[m] = o1;
      u64 o2 = __shfl_xor(qm[m], off, 64); if (o2 > qm[m]) qm[m] = o2;
    }
  }
  if ((l & 31) == 0) {
    int h = l >> 5;
#pragma unroll
    for (int m = 0; m < 4; m++) {
      int p = (n0 >> 3) + ((w >> 1) * 8) + m * 2 + h;   // global prototype idx
      if (p < P_) {
        atomicMax(&rawslot[b * P_ + p], pm[m]);
        atomicMax(&qslot[b * P_ + p], qm[m]);
      }
    }
  }
}

// ---- greedy selection, one wave per (b,p); slots + LDS-prefetched window ----
__global__ __launch_bounds__(256) void select_kernel(const float* __restrict__ dist,
                                                     const u64* __restrict__ rawslot,
                                                     const u64* __restrict__ qslot,
                                                     const float* __restrict__ tmg,
                                                     const float* __restrict__ psel,
                                                     float* __restrict__ out) {
  __shared__ float win[4][NP_][33];   // 32-wide window +1 pad; ~4.2 KiB
  int w = threadIdx.x >> 6, lane = threadIdx.x & 63;
  int pair = blockIdx.x * 4 + w;
  int b = pair / P_, p = pair % P_;     // all 4 pairs in a block share b (200%4==0)
  const float* dbase = dist + ((size_t)b * N_TOT + p * NP_) * T_;

  bool okt = true;
#pragma unroll
  for (int c = 0; c < 8; c++) okt = okt && (tmg[b * T_ + c * 64 + lane] == 1.0f);
  bool tmones = (__ballot(okt) == ~0ULL);   // block-uniform (same b per block)

  u64 rs = rawslot[pair], qs = qslot[pair];
  float rv = deco((unsigned)(rs >> 32)); int rkey = 4095 - (int)(rs & 0xFFFFu);
  float qv = deco((unsigned)(qs >> 32)); int qkey = 4095 - (int)(qs & 0xFFFFu);

  int e0 = rkey & (T_ - 1);
  int lo = e0 - 3;
  if (lo < 0) lo = 0;
  if (lo > T_ - 32) lo = T_ - 32;       // window [lo, lo+31] covers [e0-3, e0+21]
  if (tmones) {
#pragma unroll
    for (int r2 = 0; r2 < 4; r2++) {    // 4 coalesced rounds: 2 rows x 32 f32 each
      int idx = r2 * 64 + lane;
      win[w][idx >> 5][idx & 31] = dbase[(size_t)(idx >> 5) * T_ + lo + (idx & 31)];
    }
  }
  __syncthreads();                      // unconditional: block-uniform control flow

  float valh[8]; int evh[8], sidh[8];
#pragma unroll
  for (int k = 0; k < 8; k++) { valh[k] = 0.f; evh[k] = -1; sidh[k] = 0; }
  unsigned msub = 0xFFu;
  int e_last = 0;

  for (int it = 0; it < 8; ++it) {
    float bv; int bkey;
    if (tmones) {
      if (it == 0) { bv = rv; bkey = rkey; }
      else {
        // window: it==1: e0-3..e0+3 (7 slots); it>=2: (e,e+3] (3 slots). lane = i*8+widx
        int i = lane >> 3, widx = lane & 7;
        int tw, nw;
        if (it == 1) { tw = e_last - 3 + widx; nw = 7; }
        else         { tw = e_last + 1 + widx; nw = 3; }
        bool valid = (widx < nw) && (tw >= 0) && (tw < T_) && (((msub >> i) & 1u) != 0u);
#pragma unroll
        for (int k = 0; k < 8; k++) if (tw == evh[k]) valid = false;
        float v = -3.0e38f;
        if (valid) {
          int off = tw - lo;
          v = (off >= 0 && off < 32) ? win[w][i][off]
                                     : dbase[(size_t)i * T_ + tw];   // rare post-fallback
        }
        int key = valid ? (i * T_ + tw) : 0x7FFFFFFF;
#pragma unroll
        for (int off = 32; off; off >>= 1) {
          float ov = __shfl_xor(v, off, 64);
          int  ok2 = __shfl_xor(key, off, 64);
          if (ov > v || (ov == v && ok2 < key)) { v = ov; key = ok2; }
        }
        if (v > -2.9e38f) { bv = v; bkey = key; }
        else              { bv = qv; bkey = qkey; }   // empty window -> uniform +NEG argmax
      }
    } else {
      // general path (mask not all ones): full re-scan with exact ref arithmetic
      float lv = -3.0e38f; int lkey = 0x7FFFFFFF;
      for (int i = 0; i < 8; i++) {
        bool sub_ok = ((msub >> i) & 1u) != 0u;
        const float* row = dbase + (size_t)i * T_;
        float4 u0 = *(const float4*)(row + lane * 8);
        float4 u1 = *(const float4*)(row + lane * 8 + 4);
        float uv[8] = {u0.x, u0.y, u0.z, u0.w, u1.x, u1.y, u1.z, u1.w};
#pragma unroll
        for (int j = 0; j < 8; j++) {
          int t = lane * 8 + j;
          bool act = sub_ok;
          if (it > 0) {
            int dt = t - e_last;
            act = act && (dt <= 3) && (dt >= -3);
            if (it > 1) act = act && (dt > 0);
          }
#pragma unroll
          for (int k = 0; k < 8; k++) if (t == evh[k]) act = false;
          float dm = act ? uv[j] : (uv[j] + NEG_);
          if (dm > lv) { lv = dm; lkey = i * T_ + t; }
        }
      }
#pragma unroll
      for (int off = 32; off; off >>= 1) {
        float ov = __shfl_xor(lv, off, 64);
        int  ok2 = __shfl_xor(lkey, off, 64);
        if (ov > lv || (ov == lv && ok2 < lkey)) { lv = ov; lkey = ok2; }
      }
      bv = lv; bkey = lkey;
    }
    int bi = bkey >> 9, bt = bkey & (T_ - 1);
#pragma unroll
    for (int k = 0; k < 8; k++) {
      if (it == k) { valh[k] = bv; evh[k] = bt; sidh[k] = bi; }
    }
    msub &= ~(1u << bi);
    e_last = bt;
  }

  if (lane == 0) {
    int ord[8]; unsigned used = 0;
#pragma unroll
    for (int j = 0; j < 8; j++) {    // stable argsort of sidh
      int bk = 1 << 30, bi2 = 0;
#pragma unroll
      for (int k = 0; k < 8; k++)
        if (!((used >> k) & 1u)) { int key = sidh[k] * 8 + k; if (key < bk) { bk = key; bi2 = k; } }
      ord[j] = bi2; used |= 1u << bi2;
    }
    float slots[8]; float ssum = 0.f;
#pragma unroll
    for (int i = 0; i < 8; i++) {
      slots[i] = 1.0f / (1.0f + expf(-psel[p * NP_ + i]));
      ssum += slots[i];
    }
    float fac = ssum + 1e-10f;
    float acc = 0.f;
    float vr[8]; float er[8];
#pragma unroll
    for (int j = 0; j < 8; j++) {
      float vv = 0.f, ee = 0.f;
#pragma unroll
      for (int k = 0; k < 8; k++) if (ord[j] == k) { vv = valh[k]; ee = (float)evh[k]; }
      vr[j] = vv; er[j] = ee;
    }
#pragma unroll
    for (int j = 0; j < 8; j++) acc += vr[j] * (slots[j] * 8.0f / fac);
    int bp = b * P_ + p;
    out[bp] = acc;
    out[B_ * P_ + bp] = 8.0f - acc;
#pragma unroll
    for (int j = 0; j < 8; j++) out[2 * B_ * P_ + bp * 8 + j] = er[j];
  }
}

extern "C" void kernel_launch(void* const* d_in, const int* in_sizes, int n_in,
                              void* d_out, int out_size, void* d_ws, size_t ws_size,
                              hipStream_t stream) {
  const float* x     = (const float*)d_in[0];
  const float* tm    = (const float*)d_in[1];
  const float* proto = (const float*)d_in[2];
  const float* psel  = (const float*)d_in[3];
  float* out = (float*)d_out;

  char* wsb = (char*)d_ws;
  _Float16* XH = (_Float16*)wsb;                             // 16,777,216 B
  _Float16* XL = (_Float16*)(wsb + 16777216u);               // 16,777,216 B
  _Float16* WH = (_Float16*)(wsb + 2u * 16777216u);          //  1,638,400 B
  _Float16* WL = (_Float16*)(wsb + 2u * 16777216u + 1638400u);
  float*   dist = (float*)(wsb + 2u * 16777216u + 2u * 1638400u);   // 104,857,600 B
  u64*  rawslot = (u64*)(wsb + 141688832u);                  //  51,200 B
  u64*  qslot   = rawslot + B_ * P_;                         //  51,200 B
  // total = 141,791,232 B

  norm_fused<<<dim3(B_ * T_ / 4 + N_TOT / 4), 256, 0, stream>>>(
      x, proto, XH, XL, WH, WL, rawslot);
  gemm_mfma<<<dim3(T_ / 128, (N_TOT + 255) / 256, B_), 512, 0, stream>>>(
      XH, XL, WH, WL, tm, dist, rawslot, qslot);
  select_kernel<<<dim3(B_ * P_ / 4), 256, 0, stream>>>(dist, rawslot, qslot, tm, psel, out);
}

// Round 12
// 223.986 us; speedup vs baseline: 1.1396x; 1.1396x over previous
//
#include <hip/hip_runtime.h>
#include <hip/hip_bf16.h>
#include <hip/hip_fp16.h>
#include <math.h>

#define B_    32
#define T_    512
#define D_    512
#define P_    200
#define NP_   8
#define N_TOT 1600
#define NEG_  (-100000.0f)
#define LO_SCALE 2048.0f
#define LO_INV   (1.0f/2048.0f)

typedef __attribute__((ext_vector_type(8))) _Float16 f16x8;
typedef __attribute__((ext_vector_type(4))) _Float16 f16x4;
typedef __attribute__((ext_vector_type(4))) float   f32x4;
typedef unsigned long long u64;

// global -> LDS direct copy, 16B per lane; LDS dest = wave-uniform base + lane*16
#define GLL16(gp, lp) __builtin_amdgcn_global_load_lds( \
    (const __attribute__((address_space(1))) void*)(gp), \
    (__attribute__((address_space(3))) void*)(lp), 16, 0, 0)

__device__ __forceinline__ float wave_reduce_sum(float v) {
#pragma unroll
  for (int off = 32; off; off >>= 1) v += __shfl_xor(v, off, 64);
  return v;
}

// monotone f32 -> u32 order transform and inverse
__device__ __forceinline__ unsigned ordf(float f) {
  unsigned u = __float_as_uint(f);
  return (u & 0x80000000u) ? ~u : (u | 0x80000000u);
}
__device__ __forceinline__ float deco(unsigned o) {
  unsigned u = (o & 0x80000000u) ? (o ^ 0x80000000u) : ~o;
  return __uint_as_float(u);
}
// pack: value-major, inverted key (smaller key wins ties). key = i*512 + t < 4096.
__device__ __forceinline__ u64 packvk(float v, int key) {
  return ((u64)ordf(v) << 32) | (u64)(4095 - key);
}

// ---- fused normalize: blocks [0,4096) do x rows; [4096,4496) do prototypes ----
__global__ __launch_bounds__(256) void norm_fused(const float* __restrict__ x,
                                                  const float* __restrict__ proto,
                                                  _Float16* __restrict__ xh,
                                                  _Float16* __restrict__ xl,
                                                  _Float16* __restrict__ wh,
                                                  _Float16* __restrict__ wl,
                                                  u64* __restrict__ slotbuf) {
  int lane = threadIdx.x & 63;
  if (blockIdx.x < B_ * T_ / 4) {
    int row = blockIdx.x * 4 + (threadIdx.x >> 6);   // 0..16383
    const float* xr = x + (size_t)row * D_;
    float4 v0 = *(const float4*)(xr + lane * 4);
    float4 v1 = *(const float4*)(xr + 256 + lane * 4);
    float s = v0.x*v0.x + v0.y*v0.y + v0.z*v0.z + v0.w*v0.w
            + v1.x*v1.x + v1.y*v1.y + v1.z*v1.z + v1.w*v1.w;
    s = wave_reduce_sum(s);
    float dn = fmaxf(sqrtf(s), 1e-12f);
    float f[8] = {v0.x/dn, v0.y/dn, v0.z/dn, v0.w/dn, v1.x/dn, v1.y/dn, v1.z/dn, v1.w/dn};
    f16x4 h0, h1, l0, l1;
#pragma unroll
    for (int j = 0; j < 4; j++) {
      h0[j] = (_Float16)f[j];
      l0[j] = (_Float16)((f[j] - (float)h0[j]) * LO_SCALE);
      h1[j] = (_Float16)f[4 + j];
      l1[j] = (_Float16)((f[4 + j] - (float)h1[j]) * LO_SCALE);
    }
    size_t base = (size_t)row * D_;
    *(f16x4*)(xh + base + lane * 4)       = h0;
    *(f16x4*)(xh + base + 256 + lane * 4) = h1;
    *(f16x4*)(xl + base + lane * 4)       = l0;
    *(f16x4*)(xl + base + 256 + lane * 4) = l1;
  } else {
    int wb = blockIdx.x - B_ * T_ / 4;               // 0..399
    if (wb == 0) {   // zero raw+q slots; completes before gemm in-stream
      for (int i = threadIdx.x; i < 2 * B_ * P_; i += 256) slotbuf[i] = 0ULL;
    }
    int n = wb * 4 + (threadIdx.x >> 6);             // 0..1599
    int p = n >> 3, i = n & 7;
    float v[8];
    float s = 0.f;
#pragma unroll
    for (int k = 0; k < 8; k++) {
      int d = k * 64 + lane;
      v[k] = proto[((size_t)p * D_ + d) * NP_ + i];
      s += v[k] * v[k];
    }
    s = wave_reduce_sum(s);
    float dn = fmaxf(sqrtf(s), 1e-12f);
    size_t base = (size_t)n * D_;
#pragma unroll
    for (int k = 0; k < 8; k++) {
      float f = v[k] / dn;
      _Float16 h = (_Float16)f;
      wh[base + k * 64 + lane] = h;
      wl[base + k * 64 + lane] = (_Float16)((f - (float)h) * LO_SCALE);
    }
  }
}

// ---- fp16-split MFMA GEMM + fused per-(b,p) argmax slots ----
// r9's measured-best row-major structure (128x128, chunked staging, [row][32])
// + LDS double-buffer with prefetch-before-compute, ONE barrier per K-step.
// Composition evidence: fragmajor cost +36 (r8 164 vs r9 128); dbuf+1barrier
// gain -26 (r6 138 vs r8 164); both predict rowmajor+dbuf ~= 102us.
// Schedule/iter: issue next tile's 8 GLL16 -> ds_read cur -> 48 MFMA ->
// syncthreads (vmcnt(0) lands AFTER compute: stage latency hidden under MFMA).
__global__ __launch_bounds__(256, 2) void gemm_mfma(
    const _Float16* __restrict__ XH, const _Float16* __restrict__ XL,
    const _Float16* __restrict__ WH, const _Float16* __restrict__ WL,
    const float* __restrict__ tm, float* __restrict__ dist,
    u64* __restrict__ rawslot, u64* __restrict__ qslot) {
  __shared__ _Float16 lds[2 * 16384];   // 64 KiB double buffer; per buf: Ah|Al|Xh|Xl
  const int b  = blockIdx.z;
  const int n0 = blockIdx.y * 128;
  const int t0 = blockIdx.x * 128;
  const int tid = threadIdx.x;
  const int w = tid >> 6, l = tid & 63;

  // staging: per array 512 chunks of 16B; wave w covers chunks (w*2+j)*64 + lane.
  int c0 = (w * 2 + 0) * 64 + l;
  int c1 = (w * 2 + 1) * 64 + l;
  int r0 = c0 >> 2, kc0 = (c0 & 3) * 8;
  int r1 = c1 >> 2, kc1 = (c1 & 3) * 8;
  int an0 = n0 + r0; if (an0 > N_TOT - 1) an0 = N_TOT - 1;   // clamp (stores/slots guarded)
  int an1 = n0 + r1; if (an1 > N_TOT - 1) an1 = N_TOT - 1;
  const _Float16* wh0 = WH + (size_t)an0 * D_ + kc0;
  const _Float16* wh1 = WH + (size_t)an1 * D_ + kc1;
  const _Float16* wl0 = WL + (size_t)an0 * D_ + kc0;
  const _Float16* wl1 = WL + (size_t)an1 * D_ + kc1;
  const _Float16* xh0 = XH + ((size_t)b * T_ + t0 + r0) * D_ + kc0;
  const _Float16* xh1 = XH + ((size_t)b * T_ + t0 + r1) * D_ + kc1;
  const _Float16* xl0 = XL + ((size_t)b * T_ + t0 + r0) * D_ + kc0;
  const _Float16* xl1 = XL + ((size_t)b * T_ + t0 + r1) * D_ + kc1;
  const int dA = (w * 2) * 512;          // LDS elem offsets within a buffer

#define STAGE(bufo, kk) do { \
    GLL16(wh0 + (kk), &lds[(bufo) + dA]);          GLL16(wh1 + (kk), &lds[(bufo) + dA + 512]); \
    GLL16(wl0 + (kk), &lds[(bufo) + 4096 + dA]);   GLL16(wl1 + (kk), &lds[(bufo) + 4096 + dA + 512]); \
    GLL16(xh0 + (kk), &lds[(bufo) + 8192 + dA]);   GLL16(xh1 + (kk), &lds[(bufo) + 8192 + dA + 512]); \
    GLL16(xl0 + (kk), &lds[(bufo) + 12288 + dA]);  GLL16(xl1 + (kk), &lds[(bufo) + 12288 + dA + 512]); \
  } while (0)

  const int wn = (w >> 1) * 64, wtf = (w & 1) * 64;
  const int fr = l & 15, fq = l >> 4;

  f32x4 acch[4][4], accc[4][4];
#pragma unroll
  for (int m = 0; m < 4; m++)
#pragma unroll
    for (int n = 0; n < 4; n++) { acch[m][n] = (f32x4)0.0f; accc[m][n] = (f32x4)0.0f; }

  STAGE(0, 0);
  __syncthreads();                        // prologue: tile 0 ready

  for (int kt = 0; kt < 16; ++kt) {
    const int cur = (kt & 1) * 16384;
    if (kt < 15) STAGE(cur ^ 16384, (kt + 1) * 32);   // prefetch next tile (issue only)

    f16x8 ah[4], al[4], bh[4], bl[4];
#pragma unroll
    for (int m = 0; m < 4; m++) {
      int ro = (wn + m * 16 + fr) * 32 + fq * 8;
      ah[m] = *(const f16x8*)&lds[cur + ro];
      al[m] = *(const f16x8*)&lds[cur + 4096 + ro];
    }
#pragma unroll
    for (int n = 0; n < 4; n++) {
      int ro = (wtf + n * 16 + fr) * 32 + fq * 8;
      bh[n] = *(const f16x8*)&lds[cur + 8192 + ro];
      bl[n] = *(const f16x8*)&lds[cur + 12288 + ro];
    }
#pragma unroll
    for (int m = 0; m < 4; m++)
#pragma unroll
      for (int n = 0; n < 4; n++) {
        acch[m][n] = __builtin_amdgcn_mfma_f32_16x16x32_f16(ah[m], bh[n], acch[m][n], 0, 0, 0);
        accc[m][n] = __builtin_amdgcn_mfma_f32_16x16x32_f16(ah[m], bl[n], accc[m][n], 0, 0, 0);
        accc[m][n] = __builtin_amdgcn_mfma_f32_16x16x32_f16(al[m], bh[n], accc[m][n], 0, 0, 0);
      }
    __syncthreads();   // single barrier/K-step: drains prefetch (after MFMA) + guards reuse
  }
#undef STAGE

  // epilogue: combine, mask, store, and fused (max,first-key) reduction per p-group.
  // C/D: col = lane&15, row = (lane>>4)*4 + reg
  u64 pm[4], qm[4];
#pragma unroll
  for (int m = 0; m < 4; m++) { pm[m] = 0ULL; qm[m] = 0ULL; }
#pragma unroll
  for (int n = 0; n < 4; n++) {
    int col = t0 + wtf + n * 16 + fr;   // global t
    float tmc = tm[b * T_ + col];
#pragma unroll
    for (int m = 0; m < 4; m++) {
      int nb = n0 + wn + m * 16 + fq * 4;
#pragma unroll
      for (int r = 0; r < 4; r++) {
        int nr = nb + r;
        if (nr < N_TOT) {
          float v = acch[m][n][r] + accc[m][n][r] * LO_INV;
          v = v * tmc + (1.0f - tmc) * NEG_;
          dist[((size_t)b * N_TOT + nr) * T_ + col] = v;
          int key = ((fq * 4 + r) & 7) * T_ + col;            // i*512 + t
          u64 pk = packvk(v, key);
          if (pk > pm[m]) pm[m] = pk;
          u64 qk = packvk(v + NEG_, key);                     // f32-quantized fallback
          if (qk > qm[m]) qm[m] = qk;
        }
      }
    }
  }
  // cross-lane: lanes 0-31 hold p-group 0 of each m, lanes 32-63 p-group 1
#pragma unroll
  for (int m = 0; m < 4; m++) {
#pragma unroll
    for (int off = 1; off <= 16; off <<= 1) {
      u64 o1 = __shfl_xor(pm[m], off, 64); if (o1 > pm[m]) pm[m] = o1;
      u64 o2 = __shfl_xor(qm[m], off, 64); if (o2 > qm[m]) qm[m] = o2;
    }
  }
  if ((l & 31) == 0) {
    int h = l >> 5;
#pragma unroll
    for (int m = 0; m < 4; m++) {
      int p = (n0 >> 3) + ((w >> 1) * 8) + m * 2 + h;   // global prototype idx
      if (p < P_) {
        atomicMax(&rawslot[b * P_ + p], pm[m]);
        atomicMax(&qslot[b * P_ + p], qm[m]);
      }
    }
  }
}

// ---- greedy selection, one wave per (b,p); slots + LDS-prefetched window ----
__global__ __launch_bounds__(256) void select_kernel(const float* __restrict__ dist,
                                                     const u64* __restrict__ rawslot,
                                                     const u64* __restrict__ qslot,
                                                     const float* __restrict__ tmg,
                                                     const float* __restrict__ psel,
                                                     float* __restrict__ out) {
  __shared__ float win[4][NP_][33];   // 32-wide window +1 pad; ~4.2 KiB
  int w = threadIdx.x >> 6, lane = threadIdx.x & 63;
  int pair = blockIdx.x * 4 + w;
  int b = pair / P_, p = pair % P_;     // all 4 pairs in a block share b (200%4==0)
  const float* dbase = dist + ((size_t)b * N_TOT + p * NP_) * T_;

  bool okt = true;
#pragma unroll
  for (int c = 0; c < 8; c++) okt = okt && (tmg[b * T_ + c * 64 + lane] == 1.0f);
  bool tmones = (__ballot(okt) == ~0ULL);   // block-uniform (same b per block)

  u64 rs = rawslot[pair], qs = qslot[pair];
  float rv = deco((unsigned)(rs >> 32)); int rkey = 4095 - (int)(rs & 0xFFFFu);
  float qv = deco((unsigned)(qs >> 32)); int qkey = 4095 - (int)(qs & 0xFFFFu);

  int e0 = rkey & (T_ - 1);
  int lo = e0 - 3;
  if (lo < 0) lo = 0;
  if (lo > T_ - 32) lo = T_ - 32;       // window [lo, lo+31] covers [e0-3, e0+21]
  if (tmones) {
#pragma unroll
    for (int r2 = 0; r2 < 4; r2++) {    // 4 coalesced rounds: 2 rows x 32 f32 each
      int idx = r2 * 64 + lane;
      win[w][idx >> 5][idx & 31] = dbase[(size_t)(idx >> 5) * T_ + lo + (idx & 31)];
    }
  }
  __syncthreads();                      // unconditional: block-uniform control flow

  float valh[8]; int evh[8], sidh[8];
#pragma unroll
  for (int k = 0; k < 8; k++) { valh[k] = 0.f; evh[k] = -1; sidh[k] = 0; }
  unsigned msub = 0xFFu;
  int e_last = 0;

  for (int it = 0; it < 8; ++it) {
    float bv; int bkey;
    if (tmones) {
      if (it == 0) { bv = rv; bkey = rkey; }
      else {
        // window: it==1: e0-3..e0+3 (7 slots); it>=2: (e,e+3] (3 slots). lane = i*8+widx
        int i = lane >> 3, widx = lane & 7;
        int tw, nw;
        if (it == 1) { tw = e_last - 3 + widx; nw = 7; }
        else         { tw = e_last + 1 + widx; nw = 3; }
        bool valid = (widx < nw) && (tw >= 0) && (tw < T_) && (((msub >> i) & 1u) != 0u);
#pragma unroll
        for (int k = 0; k < 8; k++) if (tw == evh[k]) valid = false;
        float v = -3.0e38f;
        if (valid) {
          int off = tw - lo;
          v = (off >= 0 && off < 32) ? win[w][i][off]
                                     : dbase[(size_t)i * T_ + tw];   // rare post-fallback
        }
        int key = valid ? (i * T_ + tw) : 0x7FFFFFFF;
#pragma unroll
        for (int off = 32; off; off >>= 1) {
          float ov = __shfl_xor(v, off, 64);
          int  ok2 = __shfl_xor(key, off, 64);
          if (ov > v || (ov == v && ok2 < key)) { v = ov; key = ok2; }
        }
        if (v > -2.9e38f) { bv = v; bkey = key; }
        else              { bv = qv; bkey = qkey; }   // empty window -> uniform +NEG argmax
      }
    } else {
      // general path (mask not all ones): full re-scan with exact ref arithmetic
      float lv = -3.0e38f; int lkey = 0x7FFFFFFF;
      for (int i = 0; i < 8; i++) {
        bool sub_ok = ((msub >> i) & 1u) != 0u;
        const float* row = dbase + (size_t)i * T_;
        float4 u0 = *(const float4*)(row + lane * 8);
        float4 u1 = *(const float4*)(row + lane * 8 + 4);
        float uv[8] = {u0.x, u0.y, u0.z, u0.w, u1.x, u1.y, u1.z, u1.w};
#pragma unroll
        for (int j = 0; j < 8; j++) {
          int t = lane * 8 + j;
          bool act = sub_ok;
          if (it > 0) {
            int dt = t - e_last;
            act = act && (dt <= 3) && (dt >= -3);
            if (it > 1) act = act && (dt > 0);
          }
#pragma unroll
          for (int k = 0; k < 8; k++) if (t == evh[k]) act = false;
          float dm = act ? uv[j] : (uv[j] + NEG_);
          if (dm > lv) { lv = dm; lkey = i * T_ + t; }
        }
      }
#pragma unroll
      for (int off = 32; off; off >>= 1) {
        float ov = __shfl_xor(lv, off, 64);
        int  ok2 = __shfl_xor(lkey, off, 64);
        if (ov > lv || (ov == lv && ok2 < lkey)) { lv = ov; lkey = ok2; }
      }
      bv = lv; bkey = lkey;
    }
    int bi = bkey >> 9, bt = bkey & (T_ - 1);
#pragma unroll
    for (int k = 0; k < 8; k++) {
      if (it == k) { valh[k] = bv; evh[k] = bt; sidh[k] = bi; }
    }
    msub &= ~(1u << bi);
    e_last = bt;
  }

  if (lane == 0) {
    int ord[8]; unsigned used = 0;
#pragma unroll
    for (int j = 0; j < 8; j++) {    // stable argsort of sidh
      int bk = 1 << 30, bi2 = 0;
#pragma unroll
      for (int k = 0; k < 8; k++)
        if (!((used >> k) & 1u)) { int key = sidh[k] * 8 + k; if (key < bk) { bk = key; bi2 = k; } }
      ord[j] = bi2; used |= 1u << bi2;
    }
    float slots[8]; float ssum = 0.f;
#pragma unroll
    for (int i = 0; i < 8; i++) {
      slots[i] = 1.0f / (1.0f + expf(-psel[p * NP_ + i]));
      ssum += slots[i];
    }
    float fac = ssum + 1e-10f;
    float acc = 0.f;
    float vr[8]; float er[8];
#pragma unroll
    for (int j = 0; j < 8; j++) {
      float vv = 0.f, ee = 0.f;
#pragma unroll
      for (int k = 0; k < 8; k++) if (ord[j] == k) { vv = valh[k]; ee = (float)evh[k]; }
      vr[j] = vv; er[j] = ee;
    }
#pragma unroll
    for (int j = 0; j < 8; j++) acc += vr[j] * (slots[j] * 8.0f / fac);
    int bp = b * P_ + p;
    out[bp] = acc;
    out[B_ * P_ + bp] = 8.0f - acc;
#pragma unroll
    for (int j = 0; j < 8; j++) out[2 * B_ * P_ + bp * 8 + j] = er[j];
  }
}

extern "C" void kernel_launch(void* const* d_in, const int* in_sizes, int n_in,
                              void* d_out, int out_size, void* d_ws, size_t ws_size,
                              hipStream_t stream) {
  const float* x     = (const float*)d_in[0];
  const float* tm    = (const float*)d_in[1];
  const float* proto = (const float*)d_in[2];
  const float* psel  = (const float*)d_in[3];
  float* out = (float*)d_out;

  char* wsb = (char*)d_ws;
  _Float16* XH = (_Float16*)wsb;                             // 16,777,216 B
  _Float16* XL = (_Float16*)(wsb + 16777216u);               // 16,777,216 B
  _Float16* WH = (_Float16*)(wsb + 2u * 16777216u);          //  1,638,400 B
  _Float16* WL = (_Float16*)(wsb + 2u * 16777216u + 1638400u);
  float*   dist = (float*)(wsb + 2u * 16777216u + 2u * 1638400u);   // 104,857,600 B
  u64*  rawslot = (u64*)(wsb + 141688832u);                  //  51,200 B
  u64*  qslot   = rawslot + B_ * P_;                         //  51,200 B
  // total = 141,791,232 B

  norm_fused<<<dim3(B_ * T_ / 4 + N_TOT / 4), 256, 0, stream>>>(
      x, proto, XH, XL, WH, WL, rawslot);
  gemm_mfma<<<dim3(T_ / 128, (N_TOT + 127) / 128, B_), 256, 0, stream>>>(
      XH, XL, WH, WL, tm, dist, rawslot, qslot);
  select_kernel<<<dim3(B_ * P_ / 4), 256, 0, stream>>>(dist, rawslot, qslot, tm, psel, out);
}